// Round 19
// baseline (248.963 us; speedup 1.0000x reference)
//
#include <hip/hip_runtime.h>

#define N_TOK 8192
#define D_DIM 1024
#define H_DIM 2048
#define E_NUM 8
#define CAP   1280

typedef __attribute__((ext_vector_type(8))) short bf16x8;
typedef __attribute__((ext_vector_type(4))) float f32x4;

__device__ inline unsigned short f2bf(float f) {
  unsigned u = __float_as_uint(f);
  u += 0x7fffu + ((u >> 16) & 1u);
  return (unsigned short)(u >> 16);
}

// Counted vmcnt wait + raw barrier (NO __syncthreads in hot loops: it forces a
// full vmcnt(0) drain before s_barrier, serializing the prefetch).
#define VMCNT(n) asm volatile("s_waitcnt vmcnt(" #n ")" ::: "memory")
#define BARRIER() asm volatile("s_barrier" ::: "memory")

// ---------------- merged transpose + fp32->bf16 for all three weights
__global__ __launch_bounds__(256) void transpose_cvt_all(const float* __restrict__ W2,
                                                         const float* __restrict__ W3,
                                                         const float* __restrict__ W1,
                                                         unsigned short* __restrict__ w2t,
                                                         unsigned short* __restrict__ w3t,
                                                         unsigned short* __restrict__ w1t) {
  __shared__ float tile[64][33];
  const int id = blockIdx.x;
  const float* src;
  unsigned short* dst;
  int R, C, bx, by, b;
  if (id < 16384) {  // W2 / W3: R=D=1024, C=H=2048
    const int q = id & 8191;
    b = q >> 10;
    const int rem = q & 1023;
    bx = rem & 63;
    by = rem >> 6;
    R = D_DIM; C = H_DIM;
    src = (id < 8192 ? W2 : W3);
    dst = (id < 8192 ? w2t : w3t);
  } else {           // W1: R=H=2048, C=D=1024
    const int q = id - 16384;
    b = q >> 10;
    const int rem = q & 1023;
    bx = rem & 31;
    by = rem >> 5;
    R = H_DIM; C = D_DIM;
    src = W1; dst = w1t;
  }
  src += (size_t)b * R * C;
  dst += (size_t)b * R * C;
  const int c0 = bx * 32, r0 = by * 64;
  const int tx = threadIdx.x & 31, ty = threadIdx.x >> 5;
#pragma unroll
  for (int i = 0; i < 8; ++i)
    tile[ty + i * 8][tx] = src[(size_t)(r0 + ty + i * 8) * C + c0 + tx];
  __syncthreads();
  const int rp = threadIdx.x & 31;
  const int cb = threadIdx.x >> 5;
#pragma unroll
  for (int it = 0; it < 4; ++it) {
    const int c = cb + it * 8;
    unsigned short v[2] = {f2bf(tile[2 * rp][c]), f2bf(tile[2 * rp + 1][c])};
    *reinterpret_cast<unsigned*>(dst + (size_t)(c0 + c) * R + r0 + 2 * rp) =
        *reinterpret_cast<unsigned*>(v);
  }
}

// ---------------- gating
__global__ __launch_bounds__(256) void gate_kernel(const float* __restrict__ x,
                                                   const float* __restrict__ Wg,
                                                   const float* __restrict__ bg,
                                                   int* __restrict__ eid,
                                                   float* __restrict__ gatew) {
  __shared__ float wg[E_NUM][D_DIM];
  const int tid = threadIdx.x;
  for (int i = tid; i < D_DIM * E_NUM; i += 256) {
    int d = i >> 3, e = i & 7;
    wg[e][d] = Wg[i];
  }
  __syncthreads();
  const int w = tid >> 6, l = tid & 63;
  const int t = blockIdx.x * 4 + w;
  const float* xr = x + (size_t)t * D_DIM;
  float acc[8] = {0, 0, 0, 0, 0, 0, 0, 0};
#pragma unroll
  for (int i = 0; i < D_DIM / 64; ++i) {
    float xv = xr[l + 64 * i];
#pragma unroll
    for (int e = 0; e < 8; ++e) acc[e] += xv * wg[e][l + 64 * i];
  }
#pragma unroll
  for (int off = 32; off >= 1; off >>= 1) {
#pragma unroll
    for (int e = 0; e < 8; ++e) acc[e] += __shfl_xor(acc[e], off);
  }
  if (l == 0) {
    float best = -1e30f;
    int bi = 0;
#pragma unroll
    for (int e = 0; e < 8; ++e) {
      acc[e] += bg[e];
      if (acc[e] > best) { best = acc[e]; bi = e; }
    }
    float s = 0.f;
#pragma unroll
    for (int e = 0; e < 8; ++e) s += __expf(acc[e] - best);
    eid[t] = bi;
    gatew[t] = 1.f / s;
  }
}

// ---------------- parallel scan: wave e ranks tokens of expert e (stable order)
// Also emits a COMPACTED work list of non-empty (e,by) 128-row blocks so the
// ffn grids dispatch only active blocks contiguously (R18 lesson: in-place
// early-exit leaves dispatch holes; wall time didn't drop).
__global__ __launch_bounds__(512) void scan_kernel(const int* __restrict__ eid,
                                                   int* __restrict__ slot,
                                                   int* __restrict__ tok_of,
                                                   int* __restrict__ work,
                                                   int* __restrict__ nwork) {
  __shared__ int se[N_TOK];  // 32 KiB
  __shared__ int nby[E_NUM];
  const int tid = threadIdx.x;
  for (int i = tid; i < N_TOK; i += 512) se[i] = eid[i];
  for (int i = tid; i < E_NUM * CAP; i += 512) tok_of[i] = -1;
  __syncthreads();
  const int e = tid >> 6;   // wave index == expert id
  const int l = tid & 63;
  const unsigned long long lower = (l == 0) ? 0ull : ((1ull << l) - 1ull);
  int cnt = 0;
  for (int base = 0; base < N_TOK; base += 64) {
    const int t = base + l;
    const bool m = (se[t] == e);
    const unsigned long long bal = __ballot(m);
    if (m) {
      const int rank = cnt + __popcll(bal & lower);
      slot[t] = rank < CAP ? rank : CAP;
      if (rank < CAP) tok_of[e * CAP + rank] = t;
    }
    cnt += __popcll(bal);  // wave-uniform
  }
  if (l == 0) {
    const int c = cnt > CAP ? CAP : cnt;
    nby[e] = (c + 127) >> 7;  // 0..10 non-empty 128-row blocks
  }
  __syncthreads();
  if (tid == 0) {
    int n = 0;
    for (int ee = 0; ee < E_NUM; ++ee)
      for (int b = 0; b < nby[ee]; ++b) work[n++] = (ee << 4) | b;
    nwork[0] = n;  // <= 80
  }
}

// ---------------- scatter x rows -> binp (bf16, zeros for empty rows) AND
// zero out[] rows of overflow tokens (merged: one launch, disjoint writes).
#define SCAT_BLKS (E_NUM * CAP / 4)  // 2560
__global__ __launch_bounds__(256) void scatter_zero_kernel(const float* __restrict__ x,
                                                           const int* __restrict__ tok_of,
                                                           const int* __restrict__ slot,
                                                           unsigned short* __restrict__ binp,
                                                           float* __restrict__ out) {
  const int l = threadIdx.x & 63;
  if (blockIdx.x < SCAT_BLKS) {
    const int row = blockIdx.x * 4 + (threadIdx.x >> 6);
    const int t = tok_of[row];
    unsigned short* dst = binp + (size_t)row * D_DIM;
    if (t >= 0) {
      const float* src = x + (size_t)t * D_DIM;
#pragma unroll
      for (int i = 0; i < 4; ++i) {
        const int d = (i * 64 + l) * 4;
        float4 v = *reinterpret_cast<const float4*>(src + d);
        unsigned short r[4] = {f2bf(v.x), f2bf(v.y), f2bf(v.z), f2bf(v.w)};
        *reinterpret_cast<uint2*>(dst + d) = *reinterpret_cast<uint2*>(r);
      }
    } else {
      uint2 z = {0u, 0u};
#pragma unroll
      for (int i = 0; i < 4; ++i) {
        const int d = (i * 64 + l) * 4;
        *reinterpret_cast<uint2*>(dst + d) = z;
      }
    }
  } else {
    const int t = (blockIdx.x - SCAT_BLKS) * 4 + (threadIdx.x >> 6);
    if (slot[t] < CAP) return;
    float4 z = {0.f, 0.f, 0.f, 0.f};
#pragma unroll
    for (int i = 0; i < 4; ++i)
      *reinterpret_cast<float4*>(out + (size_t)t * D_DIM + (i * 64 + l) * 4) = z;
  }
}

// ================= BK=64 staging (proven 0-conflict swizzle) ===============
#define TILE64 (128 * 64)

__device__ inline void stage_tile(const unsigned short* __restrict__ g, int ldg, int k0,
                                  unsigned short* lds, int w, int l) {
  const int gcol = (l & 7) ^ (l >> 3);
  const unsigned short* gsrc = g + (size_t)(w * 32 + (l >> 3)) * ldg + k0 + gcol * 8;
#pragma unroll
  for (int it = 0; it < 4; ++it) {
    __builtin_amdgcn_global_load_lds(
        (const __attribute__((address_space(1))) unsigned int*)(gsrc + (size_t)(it * 8) * ldg),
        (__attribute__((address_space(3))) unsigned int*)(lds + (w * 32 + it * 8) * 64),
        16, 0, 0);
  }
}

__device__ inline bf16x8 lds_frag(const unsigned short* lds, int row, int c16) {
  return *reinterpret_cast<const bf16x8*>(lds + row * 64 + (c16 ^ (row & 7)) * 8);
}

// ---------------- ffn1: h = silu(X@W2)*(X@W3). grid 1280; active blocks are a
// CONTIGUOUS prefix (compacted work list) -> dispatcher packs them 2/CU.
// B2/B3 double-buffered (flown a full step); A single-buffered (hot L2).
// LDS = 80 KB -> exactly 2 blocks/CU. acc2+acc3 = 128 AGPR + ~120 VGPR fills
// the (256,2) budget; do NOT add register arrays (R11/R13) or min-waves (R3).
__global__ __launch_bounds__(256, 2) void ffn1_kernel(const unsigned short* __restrict__ binp,
                                                      const unsigned short* __restrict__ w2t,
                                                      const unsigned short* __restrict__ w3t,
                                                      const int* __restrict__ work,
                                                      const int* __restrict__ nwork,
                                                      unsigned short* __restrict__ hbuf) {
  __shared__ unsigned short sA[TILE64], sB2[2][TILE64], sB3[2][TILE64];  // 80 KB
  const int id = blockIdx.x;
  if (id >= (nwork[0] << 4)) return;  // contiguous tail exits instantly
  const int item = work[id >> 4];
  const int e = item >> 4;
  const int by = item & 15;      // token 128-row block (non-empty by construction)
  const int bx = id & 15;        // h 128-col block; XCD = id%8 = bx%8 (weight pinning)
  const unsigned short* A  = binp + (size_t)e * CAP * D_DIM + (size_t)by * 128 * D_DIM;
  const unsigned short* B2 = w2t + (size_t)e * H_DIM * D_DIM + (size_t)bx * 128 * D_DIM;
  const unsigned short* B3 = w3t + (size_t)e * H_DIM * D_DIM + (size_t)bx * 128 * D_DIM;
  unsigned short* H = hbuf + (size_t)e * CAP * H_DIM;
  const int tid = threadIdx.x;
  const int l = tid & 63;
  const int w = tid >> 6, wr = w >> 1, wc = w & 1;
  f32x4 acc2[4][4] = {};
  f32x4 acc3[4][4] = {};

  // prologue: B(0) -> buf0 (8 DMA); first loop iter's VMCNT(8) waits it + A(0)
  stage_tile(B2, D_DIM, 0, sB2[0], w, l);
  stage_tile(B3, D_DIM, 0, sB3[0], w, l);

  const int NT = D_DIM / 64;  // 16
  int cur = 0;
  for (int kt = 0; kt < NT; ++kt) {
    // A first (so the FIFO lets VMCNT(8) cover it), then next-step B.
    stage_tile(A, D_DIM, kt * 64, sA, w, l);
    if (kt + 1 < NT) {
      stage_tile(B2, D_DIM, (kt + 1) * 64, sB2[cur ^ 1], w, l);
      stage_tile(B3, D_DIM, (kt + 1) * 64, sB3[cur ^ 1], w, l);
      VMCNT(8);  // drains B(kt) [one full step old] + A(kt); B(kt+1) in flight
    } else {
      VMCNT(0);
    }
    BARRIER();   // staging visible to all waves
#pragma unroll
    for (int kk = 0; kk < 2; ++kk) {
      const int c16 = kk * 4 + (l >> 4);
      bf16x8 af[4], b2f[4], b3f[4];
#pragma unroll
      for (int f = 0; f < 4; ++f) {
        af[f]  = lds_frag(sA, wr * 64 + f * 16 + (l & 15), c16);
        b2f[f] = lds_frag(sB2[cur], wc * 64 + f * 16 + (l & 15), c16);
        b3f[f] = lds_frag(sB3[cur], wc * 64 + f * 16 + (l & 15), c16);
      }
#pragma unroll
      for (int fm = 0; fm < 4; ++fm)
#pragma unroll
        for (int fn = 0; fn < 4; ++fn) {
          acc2[fm][fn] = __builtin_amdgcn_mfma_f32_16x16x32_bf16(af[fm], b2f[fn], acc2[fm][fn], 0, 0, 0);
          acc3[fm][fn] = __builtin_amdgcn_mfma_f32_16x16x32_bf16(af[fm], b3f[fn], acc3[fm][fn], 0, 0, 0);
        }
    }
    BARRIER();   // all waves done reading sA/sB[cur] before next overwrite
    cur ^= 1;
  }

  const int row0 = by * 128 + wr * 64;
  const int col0 = bx * 128 + wc * 64;
#pragma unroll
  for (int fm = 0; fm < 4; ++fm)
#pragma unroll
    for (int fn = 0; fn < 4; ++fn)
#pragma unroll
      for (int j = 0; j < 4; ++j) {
        const int row = row0 + fm * 16 + (l >> 4) * 4 + j;
        const int col = col0 + fn * 16 + (l & 15);
        const float v2 = acc2[fm][fn][j];
        const float v3 = acc3[fm][fn][j];
        const float hv = (v2 / (1.0f + __expf(-v2))) * v3;
        H[(size_t)row * H_DIM + col] = f2bf(hv);
      }
}

// ---------------- ffn2: out[t] = gate[t]*(h@W1). grid 640, compacted list.
// B double-buffered (hidden); A single-buffered (hot L2). 48 KB LDS.
__global__ __launch_bounds__(256, 2) void ffn2_kernel(const unsigned short* __restrict__ hbuf,
                                                      const unsigned short* __restrict__ w1t,
                                                      const int* __restrict__ tok_of,
                                                      const float* __restrict__ gatew,
                                                      const int* __restrict__ work,
                                                      const int* __restrict__ nwork,
                                                      float* __restrict__ out) {
  __shared__ unsigned short sA[TILE64], sB[2][TILE64];  // 48 KB
  const int id = blockIdx.x;
  if (id >= (nwork[0] << 3)) return;
  const int item = work[id >> 3];
  const int e = item >> 4;
  const int by = item & 15;      // token 128-row block
  const int bx = id & 7;         // D 128-col block; XCD = id%8 = bx
  const int* tok = tok_of + e * CAP;
  const unsigned short* A = hbuf + (size_t)e * CAP * H_DIM + (size_t)by * 128 * H_DIM;
  const unsigned short* B = w1t + (size_t)e * D_DIM * H_DIM + (size_t)bx * 128 * H_DIM;
  const int tid = threadIdx.x;
  const int l = tid & 63;
  const int w = tid >> 6, wr = w >> 1, wc = w & 1;
  f32x4 acc[4][4] = {};

  stage_tile(B, H_DIM, 0, sB[0], w, l);  // prologue B(0)

  const int NT = H_DIM / 64;  // 32
  int cur = 0;
  for (int kt = 0; kt < NT; ++kt) {
    stage_tile(A, H_DIM, kt * 64, sA, w, l);
    if (kt + 1 < NT) {
      stage_tile(B, H_DIM, (kt + 1) * 64, sB[cur ^ 1], w, l);
      VMCNT(4);  // drains B(kt) [one step old] + A(kt); B(kt+1) in flight
    } else {
      VMCNT(0);
    }
    BARRIER();
#pragma unroll
    for (int kk = 0; kk < 2; ++kk) {
      const int c16 = kk * 4 + (l >> 4);
      bf16x8 af[4], bfr[4];
#pragma unroll
      for (int f = 0; f < 4; ++f) {
        af[f]  = lds_frag(sA, wr * 64 + f * 16 + (l & 15), c16);
        bfr[f] = lds_frag(sB[cur], wc * 64 + f * 16 + (l & 15), c16);
      }
#pragma unroll
      for (int fm = 0; fm < 4; ++fm)
#pragma unroll
        for (int fn = 0; fn < 4; ++fn)
          acc[fm][fn] = __builtin_amdgcn_mfma_f32_16x16x32_bf16(af[fm], bfr[fn], acc[fm][fn], 0, 0, 0);
    }
    BARRIER();
    cur ^= 1;
  }

  const int row0 = by * 128 + wr * 64;
  const int col0 = bx * 128 + wc * 64;
#pragma unroll
  for (int fm = 0; fm < 4; ++fm)
#pragma unroll
    for (int j = 0; j < 4; ++j) {
      const int row = row0 + fm * 16 + (l >> 4) * 4 + j;
      const int t = tok[row];
      if (t >= 0) {
        const float g = gatew[t];
#pragma unroll
        for (int fn = 0; fn < 4; ++fn) {
          const int col = col0 + fn * 16 + (l & 15);
          out[(size_t)t * D_DIM + col] = g * acc[fm][fn][j];
        }
      }
    }
}

extern "C" void kernel_launch(void* const* d_in, const int* in_sizes, int n_in,
                              void* d_out, int out_size, void* d_ws, size_t ws_size,
                              hipStream_t stream) {
  const float* x  = (const float*)d_in[0];
  const float* Wg = (const float*)d_in[1];
  const float* bg = (const float*)d_in[2];
  const float* W1 = (const float*)d_in[3];
  const float* W2 = (const float*)d_in[4];
  const float* W3 = (const float*)d_in[5];
  float* out = (float*)d_out;

  char* ws = (char*)d_ws;
  unsigned short* w2t = (unsigned short*)ws; ws += (size_t)E_NUM * H_DIM * D_DIM * 2;
  unsigned short* w3t = (unsigned short*)ws; ws += (size_t)E_NUM * H_DIM * D_DIM * 2;
  unsigned short* w1t = (unsigned short*)ws; ws += (size_t)E_NUM * D_DIM * H_DIM * 2;
  unsigned short* binp = (unsigned short*)ws; ws += (size_t)E_NUM * CAP * D_DIM * 2;
  unsigned short* hbuf = (unsigned short*)ws; ws += (size_t)E_NUM * CAP * H_DIM * 2;
  int* eid = (int*)ws;    ws += (size_t)N_TOK * 4;
  float* gw = (float*)ws; ws += (size_t)N_TOK * 4;
  int* slot = (int*)ws;   ws += (size_t)N_TOK * 4;
  int* tok_of = (int*)ws; ws += (size_t)E_NUM * CAP * 4;
  int* work = (int*)ws;   ws += 128 * 4;
  int* nwork = (int*)ws;  ws += 4;

  transpose_cvt_all<<<24576, 256, 0, stream>>>(W2, W3, W1, w2t, w3t, w1t);
  gate_kernel<<<N_TOK / 4, 256, 0, stream>>>(x, Wg, bg, eid, gw);
  scan_kernel<<<1, 512, 0, stream>>>(eid, slot, tok_of, work, nwork);
  scatter_zero_kernel<<<SCAT_BLKS + N_TOK / 4, 256, 0, stream>>>(x, tok_of, slot, binp, out);
  ffn1_kernel<<<1280, 256, 0, stream>>>(binp, w2t, w3t, work, nwork, hbuf);
  ffn2_kernel<<<640, 256, 0, stream>>>(hbuf, w1t, tok_of, gw, work, nwork, out);
}

// Round 20
// 235.477 us; speedup vs baseline: 1.0573x; 1.0573x over previous
//
#include <hip/hip_runtime.h>

#define N_TOK 8192
#define D_DIM 1024
#define H_DIM 2048
#define E_NUM 8
#define CAP   1280

typedef __attribute__((ext_vector_type(8))) short bf16x8;
typedef __attribute__((ext_vector_type(4))) float f32x4;

__device__ inline unsigned short f2bf(float f) {
  unsigned u = __float_as_uint(f);
  u += 0x7fffu + ((u >> 16) & 1u);
  return (unsigned short)(u >> 16);
}

// Counted vmcnt wait + raw barrier (NO __syncthreads in hot loops: it forces a
// full vmcnt(0) drain before s_barrier, serializing the prefetch).
#define VMCNT(n) asm volatile("s_waitcnt vmcnt(" #n ")" ::: "memory")
#define BARRIER() asm volatile("s_barrier" ::: "memory")

// m204 bijective chunked-XCD remap over the active prefix [0, na):
// hardware XCD = id%8; give each XCD a CONTIGUOUS chunk of work ids.
__device__ inline int xcd_chunked(int id, int na) {
  const int xcd = id & 7, pos = id >> 3;
  const int q = na >> 3, r = na & 7;
  return (xcd < r ? xcd * (q + 1) : r * (q + 1) + (xcd - r) * q) + pos;
}

// ---------------- merged transpose + fp32->bf16 for all three weights
__global__ __launch_bounds__(256) void transpose_cvt_all(const float* __restrict__ W2,
                                                         const float* __restrict__ W3,
                                                         const float* __restrict__ W1,
                                                         unsigned short* __restrict__ w2t,
                                                         unsigned short* __restrict__ w3t,
                                                         unsigned short* __restrict__ w1t) {
  __shared__ float tile[64][33];
  const int id = blockIdx.x;
  const float* src;
  unsigned short* dst;
  int R, C, bx, by, b;
  if (id < 16384) {  // W2 / W3: R=D=1024, C=H=2048
    const int q = id & 8191;
    b = q >> 10;
    const int rem = q & 1023;
    bx = rem & 63;
    by = rem >> 6;
    R = D_DIM; C = H_DIM;
    src = (id < 8192 ? W2 : W3);
    dst = (id < 8192 ? w2t : w3t);
  } else {           // W1: R=H=2048, C=D=1024
    const int q = id - 16384;
    b = q >> 10;
    const int rem = q & 1023;
    bx = rem & 31;
    by = rem >> 5;
    R = H_DIM; C = D_DIM;
    src = W1; dst = w1t;
  }
  src += (size_t)b * R * C;
  dst += (size_t)b * R * C;
  const int c0 = bx * 32, r0 = by * 64;
  const int tx = threadIdx.x & 31, ty = threadIdx.x >> 5;
#pragma unroll
  for (int i = 0; i < 8; ++i)
    tile[ty + i * 8][tx] = src[(size_t)(r0 + ty + i * 8) * C + c0 + tx];
  __syncthreads();
  const int rp = threadIdx.x & 31;
  const int cb = threadIdx.x >> 5;
#pragma unroll
  for (int it = 0; it < 4; ++it) {
    const int c = cb + it * 8;
    unsigned short v[2] = {f2bf(tile[2 * rp][c]), f2bf(tile[2 * rp + 1][c])};
    *reinterpret_cast<unsigned*>(dst + (size_t)(c0 + c) * R + r0 + 2 * rp) =
        *reinterpret_cast<unsigned*>(v);
  }
}

// ---------------- gating
__global__ __launch_bounds__(256) void gate_kernel(const float* __restrict__ x,
                                                   const float* __restrict__ Wg,
                                                   const float* __restrict__ bg,
                                                   int* __restrict__ eid,
                                                   float* __restrict__ gatew) {
  __shared__ float wg[E_NUM][D_DIM];
  const int tid = threadIdx.x;
  for (int i = tid; i < D_DIM * E_NUM; i += 256) {
    int d = i >> 3, e = i & 7;
    wg[e][d] = Wg[i];
  }
  __syncthreads();
  const int w = tid >> 6, l = tid & 63;
  const int t = blockIdx.x * 4 + w;
  const float* xr = x + (size_t)t * D_DIM;
  float acc[8] = {0, 0, 0, 0, 0, 0, 0, 0};
#pragma unroll
  for (int i = 0; i < D_DIM / 64; ++i) {
    float xv = xr[l + 64 * i];
#pragma unroll
    for (int e = 0; e < 8; ++e) acc[e] += xv * wg[e][l + 64 * i];
  }
#pragma unroll
  for (int off = 32; off >= 1; off >>= 1) {
#pragma unroll
    for (int e = 0; e < 8; ++e) acc[e] += __shfl_xor(acc[e], off);
  }
  if (l == 0) {
    float best = -1e30f;
    int bi = 0;
#pragma unroll
    for (int e = 0; e < 8; ++e) {
      acc[e] += bg[e];
      if (acc[e] > best) { best = acc[e]; bi = e; }
    }
    float s = 0.f;
#pragma unroll
    for (int e = 0; e < 8; ++e) s += __expf(acc[e] - best);
    eid[t] = bi;
    gatew[t] = 1.f / s;
  }
}

// ---------------- parallel scan + compacted work list (expert-major order)
__global__ __launch_bounds__(512) void scan_kernel(const int* __restrict__ eid,
                                                   int* __restrict__ slot,
                                                   int* __restrict__ tok_of,
                                                   int* __restrict__ work,
                                                   int* __restrict__ nwork) {
  __shared__ int se[N_TOK];  // 32 KiB
  __shared__ int nby[E_NUM];
  const int tid = threadIdx.x;
  for (int i = tid; i < N_TOK; i += 512) se[i] = eid[i];
  for (int i = tid; i < E_NUM * CAP; i += 512) tok_of[i] = -1;
  __syncthreads();
  const int e = tid >> 6;   // wave index == expert id
  const int l = tid & 63;
  const unsigned long long lower = (l == 0) ? 0ull : ((1ull << l) - 1ull);
  int cnt = 0;
  for (int base = 0; base < N_TOK; base += 64) {
    const int t = base + l;
    const bool m = (se[t] == e);
    const unsigned long long bal = __ballot(m);
    if (m) {
      const int rank = cnt + __popcll(bal & lower);
      slot[t] = rank < CAP ? rank : CAP;
      if (rank < CAP) tok_of[e * CAP + rank] = t;
    }
    cnt += __popcll(bal);  // wave-uniform
  }
  if (l == 0) {
    const int c = cnt > CAP ? CAP : cnt;
    nby[e] = (c + 127) >> 7;  // 0..10 non-empty 128-row blocks
  }
  __syncthreads();
  if (tid == 0) {
    int n = 0;
    for (int ee = 0; ee < E_NUM; ++ee)
      for (int b = 0; b < nby[ee]; ++b) work[n++] = (ee << 4) | b;
    nwork[0] = n;  // <= 80
  }
}

// ---------------- scatter x rows -> binp (bf16, zeros for empty rows) AND
// zero out[] rows of overflow tokens (merged: one launch, disjoint writes).
#define SCAT_BLKS (E_NUM * CAP / 4)  // 2560
__global__ __launch_bounds__(256) void scatter_zero_kernel(const float* __restrict__ x,
                                                           const int* __restrict__ tok_of,
                                                           const int* __restrict__ slot,
                                                           unsigned short* __restrict__ binp,
                                                           float* __restrict__ out) {
  const int l = threadIdx.x & 63;
  if (blockIdx.x < SCAT_BLKS) {
    const int row = blockIdx.x * 4 + (threadIdx.x >> 6);
    const int t = tok_of[row];
    unsigned short* dst = binp + (size_t)row * D_DIM;
    if (t >= 0) {
      const float* src = x + (size_t)t * D_DIM;
#pragma unroll
      for (int i = 0; i < 4; ++i) {
        const int d = (i * 64 + l) * 4;
        float4 v = *reinterpret_cast<const float4*>(src + d);
        unsigned short r[4] = {f2bf(v.x), f2bf(v.y), f2bf(v.z), f2bf(v.w)};
        *reinterpret_cast<uint2*>(dst + d) = *reinterpret_cast<uint2*>(r);
      }
    } else {
      uint2 z = {0u, 0u};
#pragma unroll
      for (int i = 0; i < 4; ++i) {
        const int d = (i * 64 + l) * 4;
        *reinterpret_cast<uint2*>(dst + d) = z;
      }
    }
  } else {
    const int t = (blockIdx.x - SCAT_BLKS) * 4 + (threadIdx.x >> 6);
    if (slot[t] < CAP) return;
    float4 z = {0.f, 0.f, 0.f, 0.f};
#pragma unroll
    for (int i = 0; i < 4; ++i)
      *reinterpret_cast<float4*>(out + (size_t)t * D_DIM + (i * 64 + l) * 4) = z;
  }
}

// ================= BK=64 staging (proven 0-conflict swizzle) ===============
#define TILE64 (128 * 64)

__device__ inline void stage_tile(const unsigned short* __restrict__ g, int ldg, int k0,
                                  unsigned short* lds, int w, int l) {
  const int gcol = (l & 7) ^ (l >> 3);
  const unsigned short* gsrc = g + (size_t)(w * 32 + (l >> 3)) * ldg + k0 + gcol * 8;
#pragma unroll
  for (int it = 0; it < 4; ++it) {
    __builtin_amdgcn_global_load_lds(
        (const __attribute__((address_space(1))) unsigned int*)(gsrc + (size_t)(it * 8) * ldg),
        (__attribute__((address_space(3))) unsigned int*)(lds + (w * 32 + it * 8) * 64),
        16, 0, 0);
  }
}

__device__ inline bf16x8 lds_frag(const unsigned short* lds, int row, int c16) {
  return *reinterpret_cast<const bf16x8*>(lds + row * 64 + (c16 ^ (row & 7)) * 8);
}

// ---------------- ffn1: h = silu(X@W2)*(X@W3). grid 1280.
// Compacted work list (R19: +7 µs) + chunked-XCD remap (R18 locality lesson):
// each XCD owns a contiguous run of expert-major work -> ~1 expert's weights
// per XCD L2. Inactive tail exits instantly.
// B2/B3 double-buffered; A single-buffered (hot L2). LDS 80 KB -> 2 blocks/CU.
// acc2+acc3 = 128 AGPR + ~120 VGPR fills the (256,2) budget; do NOT add
// register arrays (R11/R13 spilled) or raise min-waves (R3 spilled).
__global__ __launch_bounds__(256, 2) void ffn1_kernel(const unsigned short* __restrict__ binp,
                                                      const unsigned short* __restrict__ w2t,
                                                      const unsigned short* __restrict__ w3t,
                                                      const int* __restrict__ work,
                                                      const int* __restrict__ nwork,
                                                      unsigned short* __restrict__ hbuf) {
  __shared__ unsigned short sA[TILE64], sB2[2][TILE64], sB3[2][TILE64];  // 80 KB
  const int na = nwork[0] << 4;
  const int id = blockIdx.x;
  if (id >= na) return;  // inactive tail exits instantly
  const int wg = xcd_chunked(id, na);  // XCD(id%8) owns contiguous wg chunk
  const int item = work[wg >> 4];
  const int e = item >> 4;
  const int by = item & 15;      // token 128-row block (non-empty)
  const int bx = wg & 15;        // h 128-col block
  const unsigned short* A  = binp + (size_t)e * CAP * D_DIM + (size_t)by * 128 * D_DIM;
  const unsigned short* B2 = w2t + (size_t)e * H_DIM * D_DIM + (size_t)bx * 128 * D_DIM;
  const unsigned short* B3 = w3t + (size_t)e * H_DIM * D_DIM + (size_t)bx * 128 * D_DIM;
  unsigned short* H = hbuf + (size_t)e * CAP * H_DIM;
  const int tid = threadIdx.x;
  const int l = tid & 63;
  const int w = tid >> 6, wr = w >> 1, wc = w & 1;
  f32x4 acc2[4][4] = {};
  f32x4 acc3[4][4] = {};

  // prologue: B(0) -> buf0 (8 DMA); first loop iter's VMCNT(8) waits it + A(0)
  stage_tile(B2, D_DIM, 0, sB2[0], w, l);
  stage_tile(B3, D_DIM, 0, sB3[0], w, l);

  const int NT = D_DIM / 64;  // 16
  int cur = 0;
  for (int kt = 0; kt < NT; ++kt) {
    // A first (so the FIFO lets VMCNT(8) cover it), then next-step B.
    stage_tile(A, D_DIM, kt * 64, sA, w, l);
    if (kt + 1 < NT) {
      stage_tile(B2, D_DIM, (kt + 1) * 64, sB2[cur ^ 1], w, l);
      stage_tile(B3, D_DIM, (kt + 1) * 64, sB3[cur ^ 1], w, l);
      VMCNT(8);  // drains B(kt) [one full step old] + A(kt); B(kt+1) in flight
    } else {
      VMCNT(0);
    }
    BARRIER();   // staging visible to all waves
#pragma unroll
    for (int kk = 0; kk < 2; ++kk) {
      const int c16 = kk * 4 + (l >> 4);
      bf16x8 af[4], b2f[4], b3f[4];
#pragma unroll
      for (int f = 0; f < 4; ++f) {
        af[f]  = lds_frag(sA, wr * 64 + f * 16 + (l & 15), c16);
        b2f[f] = lds_frag(sB2[cur], wc * 64 + f * 16 + (l & 15), c16);
        b3f[f] = lds_frag(sB3[cur], wc * 64 + f * 16 + (l & 15), c16);
      }
#pragma unroll
      for (int fm = 0; fm < 4; ++fm)
#pragma unroll
        for (int fn = 0; fn < 4; ++fn) {
          acc2[fm][fn] = __builtin_amdgcn_mfma_f32_16x16x32_bf16(af[fm], b2f[fn], acc2[fm][fn], 0, 0, 0);
          acc3[fm][fn] = __builtin_amdgcn_mfma_f32_16x16x32_bf16(af[fm], b3f[fn], acc3[fm][fn], 0, 0, 0);
        }
    }
    BARRIER();   // all waves done reading sA/sB[cur] before next overwrite
    cur ^= 1;
  }

  const int row0 = by * 128 + wr * 64;
  const int col0 = bx * 128 + wc * 64;
#pragma unroll
  for (int fm = 0; fm < 4; ++fm)
#pragma unroll
    for (int fn = 0; fn < 4; ++fn)
#pragma unroll
      for (int j = 0; j < 4; ++j) {
        const int row = row0 + fm * 16 + (l >> 4) * 4 + j;
        const int col = col0 + fn * 16 + (l & 15);
        const float v2 = acc2[fm][fn][j];
        const float v3 = acc3[fm][fn][j];
        const float hv = (v2 / (1.0f + __expf(-v2))) * v3;
        H[(size_t)row * H_DIM + col] = f2bf(hv);
      }
}

// ---------------- ffn2: out[t] = gate[t]*(h@W1). grid 640, compacted+chunked.
// B double-buffered (hidden); A single-buffered (hot L2). 48 KB LDS.
__global__ __launch_bounds__(256, 2) void ffn2_kernel(const unsigned short* __restrict__ hbuf,
                                                      const unsigned short* __restrict__ w1t,
                                                      const int* __restrict__ tok_of,
                                                      const float* __restrict__ gatew,
                                                      const int* __restrict__ work,
                                                      const int* __restrict__ nwork,
                                                      float* __restrict__ out) {
  __shared__ unsigned short sA[TILE64], sB[2][TILE64];  // 48 KB
  const int na = nwork[0] << 3;
  const int id = blockIdx.x;
  if (id >= na) return;
  const int wg = xcd_chunked(id, na);
  const int item = work[wg >> 3];
  const int e = item >> 4;
  const int by = item & 15;      // token 128-row block
  const int bx = wg & 7;         // D 128-col block
  const int* tok = tok_of + e * CAP;
  const unsigned short* A = hbuf + (size_t)e * CAP * H_DIM + (size_t)by * 128 * H_DIM;
  const unsigned short* B = w1t + (size_t)e * D_DIM * H_DIM + (size_t)bx * 128 * H_DIM;
  const int tid = threadIdx.x;
  const int l = tid & 63;
  const int w = tid >> 6, wr = w >> 1, wc = w & 1;
  f32x4 acc[4][4] = {};

  stage_tile(B, H_DIM, 0, sB[0], w, l);  // prologue B(0)

  const int NT = H_DIM / 64;  // 32
  int cur = 0;
  for (int kt = 0; kt < NT; ++kt) {
    stage_tile(A, H_DIM, kt * 64, sA, w, l);
    if (kt + 1 < NT) {
      stage_tile(B, H_DIM, (kt + 1) * 64, sB[cur ^ 1], w, l);
      VMCNT(4);  // drains B(kt) [one step old] + A(kt); B(kt+1) in flight
    } else {
      VMCNT(0);
    }
    BARRIER();
#pragma unroll
    for (int kk = 0; kk < 2; ++kk) {
      const int c16 = kk * 4 + (l >> 4);
      bf16x8 af[4], bfr[4];
#pragma unroll
      for (int f = 0; f < 4; ++f) {
        af[f]  = lds_frag(sA, wr * 64 + f * 16 + (l & 15), c16);
        bfr[f] = lds_frag(sB[cur], wc * 64 + f * 16 + (l & 15), c16);
      }
#pragma unroll
      for (int fm = 0; fm < 4; ++fm)
#pragma unroll
        for (int fn = 0; fn < 4; ++fn)
          acc[fm][fn] = __builtin_amdgcn_mfma_f32_16x16x32_bf16(af[fm], bfr[fn], acc[fm][fn], 0, 0, 0);
    }
    BARRIER();
    cur ^= 1;
  }

  const int row0 = by * 128 + wr * 64;
  const int col0 = bx * 128 + wc * 64;
#pragma unroll
  for (int fm = 0; fm < 4; ++fm)
#pragma unroll
    for (int j = 0; j < 4; ++j) {
      const int row = row0 + fm * 16 + (l >> 4) * 4 + j;
      const int t = tok[row];
      if (t >= 0) {
        const float g = gatew[t];
#pragma unroll
        for (int fn = 0; fn < 4; ++fn) {
          const int col = col0 + fn * 16 + (l & 15);
          out[(size_t)t * D_DIM + col] = g * acc[fm][fn][j];
        }
      }
    }
}

extern "C" void kernel_launch(void* const* d_in, const int* in_sizes, int n_in,
                              void* d_out, int out_size, void* d_ws, size_t ws_size,
                              hipStream_t stream) {
  const float* x  = (const float*)d_in[0];
  const float* Wg = (const float*)d_in[1];
  const float* bg = (const float*)d_in[2];
  const float* W1 = (const float*)d_in[3];
  const float* W2 = (const float*)d_in[4];
  const float* W3 = (const float*)d_in[5];
  float* out = (float*)d_out;

  char* ws = (char*)d_ws;
  unsigned short* w2t = (unsigned short*)ws; ws += (size_t)E_NUM * H_DIM * D_DIM * 2;
  unsigned short* w3t = (unsigned short*)ws; ws += (size_t)E_NUM * H_DIM * D_DIM * 2;
  unsigned short* w1t = (unsigned short*)ws; ws += (size_t)E_NUM * D_DIM * H_DIM * 2;
  unsigned short* binp = (unsigned short*)ws; ws += (size_t)E_NUM * CAP * D_DIM * 2;
  unsigned short* hbuf = (unsigned short*)ws; ws += (size_t)E_NUM * CAP * H_DIM * 2;
  int* eid = (int*)ws;    ws += (size_t)N_TOK * 4;
  float* gw = (float*)ws; ws += (size_t)N_TOK * 4;
  int* slot = (int*)ws;   ws += (size_t)N_TOK * 4;
  int* tok_of = (int*)ws; ws += (size_t)E_NUM * CAP * 4;
  int* work = (int*)ws;   ws += 128 * 4;
  int* nwork = (int*)ws;  ws += 4;

  transpose_cvt_all<<<24576, 256, 0, stream>>>(W2, W3, W1, w2t, w3t, w1t);
  gate_kernel<<<N_TOK / 4, 256, 0, stream>>>(x, Wg, bg, eid, gw);
  scan_kernel<<<1, 512, 0, stream>>>(eid, slot, tok_of, work, nwork);
  scatter_zero_kernel<<<SCAT_BLKS + N_TOK / 4, 256, 0, stream>>>(x, tok_of, slot, binp, out);
  ffn1_kernel<<<1280, 256, 0, stream>>>(binp, w2t, w3t, work, nwork, hbuf);
  ffn2_kernel<<<640, 256, 0, stream>>>(hbuf, w1t, tok_of, gw, work, nwork, out);
}

// Round 21
// 227.295 us; speedup vs baseline: 1.0953x; 1.0360x over previous
//
#include <hip/hip_runtime.h>

#define N_TOK 8192
#define D_DIM 1024
#define H_DIM 2048
#define E_NUM 8
#define CAP   1280

typedef __attribute__((ext_vector_type(8))) short bf16x8;
typedef __attribute__((ext_vector_type(4))) float f32x4;

__device__ inline unsigned short f2bf(float f) {
  unsigned u = __float_as_uint(f);
  u += 0x7fffu + ((u >> 16) & 1u);
  return (unsigned short)(u >> 16);
}

// Counted vmcnt wait + raw barrier (NO __syncthreads in hot loops: it forces a
// full vmcnt(0) drain before s_barrier, serializing the prefetch).
#define VMCNT(n) asm volatile("s_waitcnt vmcnt(" #n ")" ::: "memory")
#define BARRIER() asm volatile("s_barrier" ::: "memory")

// m204 bijective chunked-XCD remap over the active prefix [0, na):
// hardware XCD = id%8; give each XCD a CONTIGUOUS chunk of work ids.
__device__ inline int xcd_chunked(int id, int na) {
  const int xcd = id & 7, pos = id >> 3;
  const int q = na >> 3, r = na & 7;
  return (xcd < r ? xcd * (q + 1) : r * (q + 1) + (xcd - r) * q) + pos;
}

// ---------------- merged transpose + fp32->bf16 for all three weights
__global__ __launch_bounds__(256) void transpose_cvt_all(const float* __restrict__ W2,
                                                         const float* __restrict__ W3,
                                                         const float* __restrict__ W1,
                                                         unsigned short* __restrict__ w2t,
                                                         unsigned short* __restrict__ w3t,
                                                         unsigned short* __restrict__ w1t) {
  __shared__ float tile[64][33];
  const int id = blockIdx.x;
  const float* src;
  unsigned short* dst;
  int R, C, bx, by, b;
  if (id < 16384) {  // W2 / W3: R=D=1024, C=H=2048
    const int q = id & 8191;
    b = q >> 10;
    const int rem = q & 1023;
    bx = rem & 63;
    by = rem >> 6;
    R = D_DIM; C = H_DIM;
    src = (id < 8192 ? W2 : W3);
    dst = (id < 8192 ? w2t : w3t);
  } else {           // W1: R=H=2048, C=D=1024
    const int q = id - 16384;
    b = q >> 10;
    const int rem = q & 1023;
    bx = rem & 31;
    by = rem >> 5;
    R = H_DIM; C = D_DIM;
    src = W1; dst = w1t;
  }
  src += (size_t)b * R * C;
  dst += (size_t)b * R * C;
  const int c0 = bx * 32, r0 = by * 64;
  const int tx = threadIdx.x & 31, ty = threadIdx.x >> 5;
#pragma unroll
  for (int i = 0; i < 8; ++i)
    tile[ty + i * 8][tx] = src[(size_t)(r0 + ty + i * 8) * C + c0 + tx];
  __syncthreads();
  const int rp = threadIdx.x & 31;
  const int cb = threadIdx.x >> 5;
#pragma unroll
  for (int it = 0; it < 4; ++it) {
    const int c = cb + it * 8;
    unsigned short v[2] = {f2bf(tile[2 * rp][c]), f2bf(tile[2 * rp + 1][c])};
    *reinterpret_cast<unsigned*>(dst + (size_t)(c0 + c) * R + r0 + 2 * rp) =
        *reinterpret_cast<unsigned*>(v);
  }
}

// ---------------- gating
__global__ __launch_bounds__(256) void gate_kernel(const float* __restrict__ x,
                                                   const float* __restrict__ Wg,
                                                   const float* __restrict__ bg,
                                                   int* __restrict__ eid,
                                                   float* __restrict__ gatew) {
  __shared__ float wg[E_NUM][D_DIM];
  const int tid = threadIdx.x;
  for (int i = tid; i < D_DIM * E_NUM; i += 256) {
    int d = i >> 3, e = i & 7;
    wg[e][d] = Wg[i];
  }
  __syncthreads();
  const int w = tid >> 6, l = tid & 63;
  const int t = blockIdx.x * 4 + w;
  const float* xr = x + (size_t)t * D_DIM;
  float acc[8] = {0, 0, 0, 0, 0, 0, 0, 0};
#pragma unroll
  for (int i = 0; i < D_DIM / 64; ++i) {
    float xv = xr[l + 64 * i];
#pragma unroll
    for (int e = 0; e < 8; ++e) acc[e] += xv * wg[e][l + 64 * i];
  }
#pragma unroll
  for (int off = 32; off >= 1; off >>= 1) {
#pragma unroll
    for (int e = 0; e < 8; ++e) acc[e] += __shfl_xor(acc[e], off);
  }
  if (l == 0) {
    float best = -1e30f;
    int bi = 0;
#pragma unroll
    for (int e = 0; e < 8; ++e) {
      acc[e] += bg[e];
      if (acc[e] > best) { best = acc[e]; bi = e; }
    }
    float s = 0.f;
#pragma unroll
    for (int e = 0; e < 8; ++e) s += __expf(acc[e] - best);
    eid[t] = bi;
    gatew[t] = 1.f / s;
  }
}

// ---------------- parallel scan + compacted work list (expert-major order)
__global__ __launch_bounds__(512) void scan_kernel(const int* __restrict__ eid,
                                                   int* __restrict__ slot,
                                                   int* __restrict__ tok_of,
                                                   int* __restrict__ work,
                                                   int* __restrict__ nwork) {
  __shared__ int se[N_TOK];  // 32 KiB
  __shared__ int nby[E_NUM];
  const int tid = threadIdx.x;
  for (int i = tid; i < N_TOK; i += 512) se[i] = eid[i];
  for (int i = tid; i < E_NUM * CAP; i += 512) tok_of[i] = -1;
  __syncthreads();
  const int e = tid >> 6;   // wave index == expert id
  const int l = tid & 63;
  const unsigned long long lower = (l == 0) ? 0ull : ((1ull << l) - 1ull);
  int cnt = 0;
  for (int base = 0; base < N_TOK; base += 64) {
    const int t = base + l;
    const bool m = (se[t] == e);
    const unsigned long long bal = __ballot(m);
    if (m) {
      const int rank = cnt + __popcll(bal & lower);
      slot[t] = rank < CAP ? rank : CAP;
      if (rank < CAP) tok_of[e * CAP + rank] = t;
    }
    cnt += __popcll(bal);  // wave-uniform
  }
  if (l == 0) {
    const int c = cnt > CAP ? CAP : cnt;
    nby[e] = (c + 127) >> 7;  // 0..10 non-empty 128-row blocks
  }
  __syncthreads();
  if (tid == 0) {
    int n = 0;
    for (int ee = 0; ee < E_NUM; ++ee)
      for (int b = 0; b < nby[ee]; ++b) work[n++] = (ee << 4) | b;
    nwork[0] = n;  // <= 80
  }
}

// ---------------- scatter x rows -> binp (bf16, zeros for empty rows) AND
// zero out[] rows of overflow tokens (merged: one launch, disjoint writes).
#define SCAT_BLKS (E_NUM * CAP / 4)  // 2560
__global__ __launch_bounds__(256) void scatter_zero_kernel(const float* __restrict__ x,
                                                           const int* __restrict__ tok_of,
                                                           const int* __restrict__ slot,
                                                           unsigned short* __restrict__ binp,
                                                           float* __restrict__ out) {
  const int l = threadIdx.x & 63;
  if (blockIdx.x < SCAT_BLKS) {
    const int row = blockIdx.x * 4 + (threadIdx.x >> 6);
    const int t = tok_of[row];
    unsigned short* dst = binp + (size_t)row * D_DIM;
    if (t >= 0) {
      const float* src = x + (size_t)t * D_DIM;
#pragma unroll
      for (int i = 0; i < 4; ++i) {
        const int d = (i * 64 + l) * 4;
        float4 v = *reinterpret_cast<const float4*>(src + d);
        unsigned short r[4] = {f2bf(v.x), f2bf(v.y), f2bf(v.z), f2bf(v.w)};
        *reinterpret_cast<uint2*>(dst + d) = *reinterpret_cast<uint2*>(r);
      }
    } else {
      uint2 z = {0u, 0u};
#pragma unroll
      for (int i = 0; i < 4; ++i) {
        const int d = (i * 64 + l) * 4;
        *reinterpret_cast<uint2*>(dst + d) = z;
      }
    }
  } else {
    const int t = (blockIdx.x - SCAT_BLKS) * 4 + (threadIdx.x >> 6);
    if (slot[t] < CAP) return;
    float4 z = {0.f, 0.f, 0.f, 0.f};
#pragma unroll
    for (int i = 0; i < 4; ++i)
      *reinterpret_cast<float4*>(out + (size_t)t * D_DIM + (i * 64 + l) * 4) = z;
  }
}

// ================= BK=64 staging (proven 0-conflict swizzle) ===============
#define TILE64 (128 * 64)

__device__ inline void stage_tile(const unsigned short* __restrict__ g, int ldg, int k0,
                                  unsigned short* lds, int w, int l) {
  const int gcol = (l & 7) ^ (l >> 3);
  const unsigned short* gsrc = g + (size_t)(w * 32 + (l >> 3)) * ldg + k0 + gcol * 8;
#pragma unroll
  for (int it = 0; it < 4; ++it) {
    __builtin_amdgcn_global_load_lds(
        (const __attribute__((address_space(1))) unsigned int*)(gsrc + (size_t)(it * 8) * ldg),
        (__attribute__((address_space(3))) unsigned int*)(lds + (w * 32 + it * 8) * 64),
        16, 0, 0);
  }
}

__device__ inline bf16x8 lds_frag(const unsigned short* lds, int row, int c16) {
  return *reinterpret_cast<const bf16x8*>(lds + row * 64 + (c16 ^ (row & 7)) * 8);
}

// ---------------- ffn1: h = silu(X@W2)*(X@W3). grid 1280.
// Compacted work list + chunked-XCD remap (R20: ffn1 best, 114.9 µs).
// B2/B3 double-buffered; A single-buffered (hot L2). LDS 80 KB -> 2 blocks/CU.
// acc2+acc3 = 128 AGPR + ~120 VGPR fills the (256,2) budget; do NOT add
// register arrays (R11/R13 spilled) or raise min-waves (R3 spilled).
__global__ __launch_bounds__(256, 2) void ffn1_kernel(const unsigned short* __restrict__ binp,
                                                      const unsigned short* __restrict__ w2t,
                                                      const unsigned short* __restrict__ w3t,
                                                      const int* __restrict__ work,
                                                      const int* __restrict__ nwork,
                                                      unsigned short* __restrict__ hbuf) {
  __shared__ unsigned short sA[TILE64], sB2[2][TILE64], sB3[2][TILE64];  // 80 KB
  const int na = nwork[0] << 4;
  const int id = blockIdx.x;
  if (id >= na) return;  // inactive tail exits instantly
  const int wg = xcd_chunked(id, na);  // XCD(id%8) owns contiguous wg chunk
  const int item = work[wg >> 4];
  const int e = item >> 4;
  const int by = item & 15;      // token 128-row block (non-empty)
  const int bx = wg & 15;        // h 128-col block
  const unsigned short* A  = binp + (size_t)e * CAP * D_DIM + (size_t)by * 128 * D_DIM;
  const unsigned short* B2 = w2t + (size_t)e * H_DIM * D_DIM + (size_t)bx * 128 * D_DIM;
  const unsigned short* B3 = w3t + (size_t)e * H_DIM * D_DIM + (size_t)bx * 128 * D_DIM;
  unsigned short* H = hbuf + (size_t)e * CAP * H_DIM;
  const int tid = threadIdx.x;
  const int l = tid & 63;
  const int w = tid >> 6, wr = w >> 1, wc = w & 1;
  f32x4 acc2[4][4] = {};
  f32x4 acc3[4][4] = {};

  // prologue: B(0) -> buf0 (8 DMA); first loop iter's VMCNT(8) waits it + A(0)
  stage_tile(B2, D_DIM, 0, sB2[0], w, l);
  stage_tile(B3, D_DIM, 0, sB3[0], w, l);

  const int NT = D_DIM / 64;  // 16
  int cur = 0;
  for (int kt = 0; kt < NT; ++kt) {
    // A first (so the FIFO lets VMCNT(8) cover it), then next-step B.
    stage_tile(A, D_DIM, kt * 64, sA, w, l);
    if (kt + 1 < NT) {
      stage_tile(B2, D_DIM, (kt + 1) * 64, sB2[cur ^ 1], w, l);
      stage_tile(B3, D_DIM, (kt + 1) * 64, sB3[cur ^ 1], w, l);
      VMCNT(8);  // drains B(kt) [one full step old] + A(kt); B(kt+1) in flight
    } else {
      VMCNT(0);
    }
    BARRIER();   // staging visible to all waves
#pragma unroll
    for (int kk = 0; kk < 2; ++kk) {
      const int c16 = kk * 4 + (l >> 4);
      bf16x8 af[4], b2f[4], b3f[4];
#pragma unroll
      for (int f = 0; f < 4; ++f) {
        af[f]  = lds_frag(sA, wr * 64 + f * 16 + (l & 15), c16);
        b2f[f] = lds_frag(sB2[cur], wc * 64 + f * 16 + (l & 15), c16);
        b3f[f] = lds_frag(sB3[cur], wc * 64 + f * 16 + (l & 15), c16);
      }
#pragma unroll
      for (int fm = 0; fm < 4; ++fm)
#pragma unroll
        for (int fn = 0; fn < 4; ++fn) {
          acc2[fm][fn] = __builtin_amdgcn_mfma_f32_16x16x32_bf16(af[fm], b2f[fn], acc2[fm][fn], 0, 0, 0);
          acc3[fm][fn] = __builtin_amdgcn_mfma_f32_16x16x32_bf16(af[fm], b3f[fn], acc3[fm][fn], 0, 0, 0);
        }
    }
    BARRIER();   // all waves done reading sA/sB[cur] before next overwrite
    cur ^= 1;
  }

  const int row0 = by * 128 + wr * 64;
  const int col0 = bx * 128 + wc * 64;
#pragma unroll
  for (int fm = 0; fm < 4; ++fm)
#pragma unroll
    for (int fn = 0; fn < 4; ++fn)
#pragma unroll
      for (int j = 0; j < 4; ++j) {
        const int row = row0 + fm * 16 + (l >> 4) * 4 + j;
        const int col = col0 + fn * 16 + (l & 15);
        const float v2 = acc2[fm][fn][j];
        const float v3 = acc3[fm][fn][j];
        const float hv = (v2 / (1.0f + __expf(-v2))) * v3;
        H[(size_t)row * H_DIM + col] = f2bf(hv);
      }
}

// ---------------- ffn2: out[t] = gate[t]*(h@W1). grid 640, R18-best mapping:
// expert-per-XCD queue, by-fastest (W1 col-panel 512 KB reused 10x, one
// expert's weights pinned per XCD L2) + in-place dense-prefix early-exit.
// (R20 lesson: chunked/bx-fastest map cost ffn2 ~11 µs — weight-panel reuse
// dominates here, unlike ffn1 where compaction wins.)
__global__ __launch_bounds__(256, 2) void ffn2_kernel(const unsigned short* __restrict__ hbuf,
                                                      const unsigned short* __restrict__ w1t,
                                                      const int* __restrict__ tok_of,
                                                      const float* __restrict__ gatew,
                                                      float* __restrict__ out) {
  __shared__ unsigned short sA[TILE64], sB[2][TILE64];  // 48 KB
  const int id = (blockIdx.x & 7) * 80 + (blockIdx.x >> 3);
  const int e = id / 80;
  const int rem = id - e * 80;
  const int bx = rem / 10;       // 0..7  D 128-col block
  const int by = rem - bx * 10;  // 0..9  token 128-row block
  const int* tok = tok_of + e * CAP;
  if (tok[by * 128] < 0) return;  // block-uniform: all 128 slots empty
  const unsigned short* A = hbuf + (size_t)e * CAP * H_DIM + (size_t)by * 128 * H_DIM;
  const unsigned short* B = w1t + (size_t)e * D_DIM * H_DIM + (size_t)bx * 128 * H_DIM;
  const int tid = threadIdx.x;
  const int l = tid & 63;
  const int w = tid >> 6, wr = w >> 1, wc = w & 1;
  f32x4 acc[4][4] = {};

  stage_tile(B, H_DIM, 0, sB[0], w, l);  // prologue B(0)

  const int NT = H_DIM / 64;  // 32
  int cur = 0;
  for (int kt = 0; kt < NT; ++kt) {
    stage_tile(A, H_DIM, kt * 64, sA, w, l);
    if (kt + 1 < NT) {
      stage_tile(B, H_DIM, (kt + 1) * 64, sB[cur ^ 1], w, l);
      VMCNT(4);  // drains B(kt) [one step old] + A(kt); B(kt+1) in flight
    } else {
      VMCNT(0);
    }
    BARRIER();
#pragma unroll
    for (int kk = 0; kk < 2; ++kk) {
      const int c16 = kk * 4 + (l >> 4);
      bf16x8 af[4], bfr[4];
#pragma unroll
      for (int f = 0; f < 4; ++f) {
        af[f]  = lds_frag(sA, wr * 64 + f * 16 + (l & 15), c16);
        bfr[f] = lds_frag(sB[cur], wc * 64 + f * 16 + (l & 15), c16);
      }
#pragma unroll
      for (int fm = 0; fm < 4; ++fm)
#pragma unroll
        for (int fn = 0; fn < 4; ++fn)
          acc[fm][fn] = __builtin_amdgcn_mfma_f32_16x16x32_bf16(af[fm], bfr[fn], acc[fm][fn], 0, 0, 0);
    }
    BARRIER();
    cur ^= 1;
  }

  const int row0 = by * 128 + wr * 64;
  const int col0 = bx * 128 + wc * 64;
#pragma unroll
  for (int fm = 0; fm < 4; ++fm)
#pragma unroll
    for (int j = 0; j < 4; ++j) {
      const int row = row0 + fm * 16 + (l >> 4) * 4 + j;
      const int t = tok[row];
      if (t >= 0) {
        const float g = gatew[t];
#pragma unroll
        for (int fn = 0; fn < 4; ++fn) {
          const int col = col0 + fn * 16 + (l & 15);
          out[(size_t)t * D_DIM + col] = g * acc[fm][fn][j];
        }
      }
    }
}

extern "C" void kernel_launch(void* const* d_in, const int* in_sizes, int n_in,
                              void* d_out, int out_size, void* d_ws, size_t ws_size,
                              hipStream_t stream) {
  const float* x  = (const float*)d_in[0];
  const float* Wg = (const float*)d_in[1];
  const float* bg = (const float*)d_in[2];
  const float* W1 = (const float*)d_in[3];
  const float* W2 = (const float*)d_in[4];
  const float* W3 = (const float*)d_in[5];
  float* out = (float*)d_out;

  char* ws = (char*)d_ws;
  unsigned short* w2t = (unsigned short*)ws; ws += (size_t)E_NUM * H_DIM * D_DIM * 2;
  unsigned short* w3t = (unsigned short*)ws; ws += (size_t)E_NUM * H_DIM * D_DIM * 2;
  unsigned short* w1t = (unsigned short*)ws; ws += (size_t)E_NUM * D_DIM * H_DIM * 2;
  unsigned short* binp = (unsigned short*)ws; ws += (size_t)E_NUM * CAP * D_DIM * 2;
  unsigned short* hbuf = (unsigned short*)ws; ws += (size_t)E_NUM * CAP * H_DIM * 2;
  int* eid = (int*)ws;    ws += (size_t)N_TOK * 4;
  float* gw = (float*)ws; ws += (size_t)N_TOK * 4;
  int* slot = (int*)ws;   ws += (size_t)N_TOK * 4;
  int* tok_of = (int*)ws; ws += (size_t)E_NUM * CAP * 4;
  int* work = (int*)ws;   ws += 128 * 4;
  int* nwork = (int*)ws;  ws += 4;

  transpose_cvt_all<<<24576, 256, 0, stream>>>(W2, W3, W1, w2t, w3t, w1t);
  gate_kernel<<<N_TOK / 4, 256, 0, stream>>>(x, Wg, bg, eid, gw);
  scan_kernel<<<1, 512, 0, stream>>>(eid, slot, tok_of, work, nwork);
  scatter_zero_kernel<<<SCAT_BLKS + N_TOK / 4, 256, 0, stream>>>(x, tok_of, slot, binp, out);
  ffn1_kernel<<<1280, 256, 0, stream>>>(binp, w2t, w3t, work, nwork, hbuf);
  ffn2_kernel<<<640, 256, 0, stream>>>(hbuf, w1t, tok_of, gw, out);
}